// Round 15
// baseline (119.072 us; speedup 1.0000x reference)
//
#include <hip/hip_runtime.h>

typedef unsigned int uint;
typedef unsigned short ushort_t;

// Problem constants
#define CN 32          // channels
#define HW 4096        // H*W
#define KDIM 288       // C*9
#define PDIM 8192      // N*HW
#define NB 2           // batch

typedef __attribute__((ext_vector_type(8))) short bf16x8;
typedef __attribute__((ext_vector_type(4))) float f32x4;

static __device__ __forceinline__ ushort_t f2bf(float f) {
    uint u = __float_as_uint(f);
    uint r = (u + 0x7fffu + ((u >> 16) & 1u)) >> 16;
    return (ushort_t)r;
}

static __device__ __forceinline__ void gl_lds16(const void* g, void* l) {
    __builtin_amdgcn_global_load_lds(
        (const __attribute__((address_space(1))) unsigned int*)g,
        (__attribute__((address_space(3))) unsigned int*)l, 16, 0, 0);
}

static __device__ __forceinline__ float fast_tanh(float v) {
    // tanh(v) = 1 - 2*rcp(1+e^{2v}); rcp(inf)=0 -> +-1 exact; err ~1e-6
    float e = __expf(2.0f * v);
    return 1.0f - 2.0f * __builtin_amdgcn_rcpf(e + 1.0f);
}

// k-permutation within each 32-k group: 16B chunk slot s holds logical
// k = {g*32 + 4s..4s+3, g*32 + 16+4s..16+4s+3}. Lane kg's whole MFMA
// fragment (k = kg*4+j, 16+kg*4+j) is then ONE contiguous 16B chunk.

// ------------- prep: conv1+relu (blocks 0..511) | w2->bf16 perm + zero-out --
// (R14-proven verbatim)
__global__ __launch_bounds__(256) void prep_kernel(
    const float* __restrict__ x, const float* __restrict__ w1,
    const float* __restrict__ w2, float* __restrict__ hout,
    ushort_t* __restrict__ A_bf, float4* __restrict__ out_zero)
{
    __shared__ float w1s[KDIM];
    __shared__ float ps[2][128][4];
    int bb = blockIdx.x;
    int tid = threadIdx.x;
    if (bb < 512) {
        int n  = bb >> 8;
        int c  = (bb >> 3) & 31;
        int rg = bb & 7;
        for (int j = tid; j < KDIM; j += 256) w1s[j] = w1[c * KDIM + j];
        __syncthreads();

        int half = tid >> 7;
        int i2   = tid & 127;
        int hh   = rg * 8 + (i2 >> 4);
        int ws0  = (i2 & 15) * 4;

        float acc0 = 0.f, acc1 = 0.f, acc2 = 0.f, acc3 = 0.f;
        int ci0 = half * 16;
        for (int ci = ci0; ci < ci0 + 16; ci++) {
            const float* xp = x + (((size_t)(n * CN + ci)) << 12);
            #pragma unroll
            for (int kh = 0; kh < 3; kh++) {
                int y = hh + kh - 1;
                if ((unsigned)y >= 64u) continue;
                const float* row = xp + (y << 6);
                float4 v = *(const float4*)(row + ws0);
                float left  = (ws0 > 0)  ? row[ws0 - 1] : 0.f;
                float right = (ws0 < 60) ? row[ws0 + 4] : 0.f;
                float rb[6] = {left, v.x, v.y, v.z, v.w, right};
                const float* wp = &w1s[ci * 9 + kh * 3];
                #pragma unroll
                for (int kw = 0; kw < 3; kw++) {
                    float wgt = wp[kw];
                    acc0 = fmaf(wgt, rb[0 + kw], acc0);
                    acc1 = fmaf(wgt, rb[1 + kw], acc1);
                    acc2 = fmaf(wgt, rb[2 + kw], acc2);
                    acc3 = fmaf(wgt, rb[3 + kw], acc3);
                }
            }
        }
        ps[half][i2][0] = acc0; ps[half][i2][1] = acc1;
        ps[half][i2][2] = acc2; ps[half][i2][3] = acc3;
        __syncthreads();
        if (half == 0) {
            float4 o = make_float4(
                fmaxf(ps[0][i2][0] + ps[1][i2][0], 0.f),
                fmaxf(ps[0][i2][1] + ps[1][i2][1], 0.f),
                fmaxf(ps[0][i2][2] + ps[1][i2][2], 0.f),
                fmaxf(ps[0][i2][3] + ps[1][i2][3], 0.f));
            *(float4*)(hout + (((size_t)(n * CN + c)) << 12) + (hh << 6) + ws0) = o;
        }
    } else {
        int idx = (bb - 512) * 256 + tid;
        if (idx < 65536)
            out_zero[idx] = make_float4(0.f, 0.f, 0.f, 0.f);
        int row = idx / 36;
        int cw  = idx - row * 36;
        int g = cw >> 2, s = cw & 3;
        const float* base = w2 + (size_t)row * KDIM + g * 32;
        float4 lo = *(const float4*)(base + s * 4);
        float4 hi = *(const float4*)(base + 16 + s * 4);
        alignas(16) ushort_t o[8] = {f2bf(lo.x), f2bf(lo.y), f2bf(lo.z), f2bf(lo.w),
                                     f2bf(hi.x), f2bf(hi.y), f2bf(hi.z), f2bf(hi.w)};
        *(uint4*)(A_bf + (size_t)idx * 8) = *(const uint4*)o;
    }
}

// ------ im2col of h, P-MAJOR k-PERMUTED bf16 (R11-proven verbatim) ------
__global__ __launch_bounds__(256) void im2col_bf16_perm(
    const float* __restrict__ h, ushort_t* __restrict__ Bm)
{
    int idx = blockIdx.x * 256 + threadIdx.x;   // PDIM*36 = 294912 chunks
    int p  = idx / 36;
    int cw = idx - p * 36;
    int g = cw >> 2, s = cw & 3;
    int n  = p >> 12;
    int sp = p & 4095;
    int hh = sp >> 6;
    int w  = sp & 63;
    const float* hn = h + (((size_t)n * CN) << 12);
    alignas(16) ushort_t o[8];
    #pragma unroll
    for (int j = 0; j < 8; j++) {
        int ko = (j < 4) ? (s * 4 + j) : (12 + s * 4 + j);
        int k  = g * 32 + ko;
        int ci = (k * 57) >> 9;
        int kk = k - ci * 9;
        int kh = (kk * 11) >> 5;
        int kw = kk - kh * 3;
        int y  = hh + kh - 1;
        int xw = w + kw - 1;
        float v = 0.f;
        if ((unsigned)y < 64u && (unsigned)xw < 64u)
            v = hn[((size_t)ci << 12) + (y << 6) + xw];
        o[j] = f2bf(v);
    }
    *(uint4*)(Bm + (size_t)idx * 8) = *(const uint4*)o;
}

// --- fused: MFMA GEMM + tanh + apply (BK=64, phase-interleaved, setprio) ---
// Semantics (R5-proven). Block = (tw, cg, n), t-window 128, 256 thr, 4 waves
// 2m x 2t, per-wave 64x64 (R10-proven frag geometry/epilogue).
// K = 4 iters of 64 + tail 32. LDS: dbuf [128 rows][64k], 8 slots/row,
// swizzle phys_slot = slot ^ (row&7) (2-way free; read rows: row&7 = i16&7).
// Per iter: 2 phases (one per 32-k half): {stage 4 chunks of NEXT iter;
// ds_read af[4]+bfr[4]@kk; SBAR; lgkmcnt(0); setprio(1); 16 MFMA;
// setprio(0); SBAR}. vmcnt(0) ONCE per iter (end of phase 1) — stages span
// all 4 intra-iter barriers (T4). Tail staged full-width with 32-k source
// duplicated into both slot-halves (phys^(row&7) round-trip -> kk0 reads
// retrieve logical kg regardless); garbage half never read.
__global__ __launch_bounds__(256) void fused_gemm_apply(
    const ushort_t* __restrict__ A, const ushort_t* __restrict__ B,
    const float* __restrict__ x, float* __restrict__ out)
{
    __shared__ ushort_t AL[2][128 * 64];   // 2 x 16 KiB
    __shared__ ushort_t BL[2][128 * 64];   // 2 x 16 KiB
    __shared__ float vred[4][128];

    int tid = threadIdx.x;
    // bijective XCD swizzle: 4608 = 8 XCDs x 576 (R11-proven)
    int bid = blockIdx.x;
    int sb  = (bid & 7) * 576 + (bid >> 3);
    int tw  = sb % 288;
    int cg  = (sb / 288) & 7;
    int n   = sb / 2304;

    int lane = tid & 63, wv = tid >> 6;
    int wm = wv >> 1, wt = wv & 1;      // 2m x 2t wave grid
    int i16 = lane & 15, kg = lane >> 4;

    int T0 = tw * 128;
    int c8 = T0 >> 12;
    int q0 = T0 & 4095;

    // ---- staging geometry: 4 A-chunks + 4 B-chunks per thread per iter ----
    // chunk c (0..1023): row = c>>3, phys slot = c&7, logical l = s^(row&7);
    // global elem offset in 64-k window = (l>>2)*32 + (l&3)*8.
    const ushort_t *sA[4], *sAt[4], *sB[4], *sBt[4];
    #pragma unroll
    for (int q = 0; q < 4; q++) {
        int c = q * 256 + tid;
        int r = c >> 3, s = c & 7;
        int l = s ^ (r & 7);
        int ofs  = ((l >> 2) << 5) + ((l & 3) << 3);
        int ofsT = 256 + ((l & 3) << 3);
        size_t aRow = (size_t)((cg * 4 + (r >> 5)) * KDIM + (r & 31) * 9 + c8);
        sA[q]  = A + aRow * KDIM + ofs;
        sAt[q] = A + aRow * KDIM + ofsT;
        size_t bRow = (size_t)((n << 12) + q0 + r);
        sB[q]  = B + bRow * KDIM + ofs;
        sBt[q] = B + bRow * KDIM + ofsT;
    }
    // wave-uniform LDS dest bases (HW adds lane*16B)
    int dstq[4];
    #pragma unroll
    for (int q = 0; q < 4; q++) dstq[q] = (q * 256 + wv * 64) * 8;

#define SCHED0 __builtin_amdgcn_sched_barrier(0)
#define RD_A(mf, kk) (*(const bf16x8*)&AL[cur][(wm * 64 + (mf) * 16 + i16) * 64 \
        + (((((kk) << 2) + kg) ^ (i16 & 7)) << 3)])
#define RD_B(nf, kk) (*(const bf16x8*)&BL[cur][(wt * 64 + (nf) * 16 + i16) * 64 \
        + (((((kk) << 2) + kg) ^ (i16 & 7)) << 3)])

    f32x4 acc[4][4] = {};

    // prologue: stage iter-0 tile into buf 0
    #pragma unroll
    for (int q = 0; q < 4; q++) {
        gl_lds16(sA[q], &AL[0][dstq[q]]);
        gl_lds16(sB[q], &BL[0][dstq[q]]);
    }
    SCHED0;
    asm volatile("s_waitcnt vmcnt(0)" ::: "memory");
    SCHED0;
    __builtin_amdgcn_s_barrier();
    SCHED0;

    #pragma unroll
    for (int it = 0; it < 4; it++) {
        int cur = it & 1, nxt = cur ^ 1;
        int ko = (it + 1) * 64;

        // -------- phase 0 (kk = 0): stage next A; reads; 16 MFMA --------
        if (it < 3) {
            #pragma unroll
            for (int q = 0; q < 4; q++) gl_lds16(sA[q] + ko, &AL[nxt][dstq[q]]);
        } else {
            #pragma unroll
            for (int q = 0; q < 4; q++) gl_lds16(sAt[q], &AL[nxt][dstq[q]]);
        }
        {
            bf16x8 af[4], bfr[4];
            #pragma unroll
            for (int mf = 0; mf < 4; mf++) af[mf] = RD_A(mf, 0);
            #pragma unroll
            for (int nf = 0; nf < 4; nf++) bfr[nf] = RD_B(nf, 0);
            SCHED0;
            __builtin_amdgcn_s_barrier();
            SCHED0;
            asm volatile("s_waitcnt lgkmcnt(0)" ::: "memory");
            SCHED0;
            __builtin_amdgcn_s_setprio(1);
            #pragma unroll
            for (int mf = 0; mf < 4; mf++)
                #pragma unroll
                for (int nf = 0; nf < 4; nf++)
                    acc[mf][nf] = __builtin_amdgcn_mfma_f32_16x16x32_bf16(
                        af[mf], bfr[nf], acc[mf][nf], 0, 0, 0);
            __builtin_amdgcn_s_setprio(0);
            SCHED0;
            __builtin_amdgcn_s_barrier();
            SCHED0;
        }

        // -------- phase 1 (kk = 1): stage next B; reads; 16 MFMA --------
        if (it < 3) {
            #pragma unroll
            for (int q = 0; q < 4; q++) gl_lds16(sB[q] + ko, &BL[nxt][dstq[q]]);
        } else {
            #pragma unroll
            for (int q = 0; q < 4; q++) gl_lds16(sBt[q], &BL[nxt][dstq[q]]);
        }
        {
            bf16x8 af[4], bfr[4];
            #pragma unroll
            for (int mf = 0; mf < 4; mf++) af[mf] = RD_A(mf, 1);
            #pragma unroll
            for (int nf = 0; nf < 4; nf++) bfr[nf] = RD_B(nf, 1);
            SCHED0;
            __builtin_amdgcn_s_barrier();
            SCHED0;
            asm volatile("s_waitcnt lgkmcnt(0)" ::: "memory");
            SCHED0;
            __builtin_amdgcn_s_setprio(1);
            #pragma unroll
            for (int mf = 0; mf < 4; mf++)
                #pragma unroll
                for (int nf = 0; nf < 4; nf++)
                    acc[mf][nf] = __builtin_amdgcn_mfma_f32_16x16x32_bf16(
                        af[mf], bfr[nf], acc[mf][nf], 0, 0, 0);
            __builtin_amdgcn_s_setprio(0);
            SCHED0;
            // once-per-iter counted point: next iter's 8 stages must be
            // resident before its phase-0 reads (issued over both phases).
            asm volatile("s_waitcnt vmcnt(0)" ::: "memory");
            SCHED0;
            __builtin_amdgcn_s_barrier();
            SCHED0;
        }
    }

    // -------- tail (K 256..287): buf 0 holds tail, kk = 0 only ----------
    {
        int cur = 0;
        bf16x8 af[4], bfr[4];
        #pragma unroll
        for (int mf = 0; mf < 4; mf++) af[mf] = RD_A(mf, 0);
        #pragma unroll
        for (int nf = 0; nf < 4; nf++) bfr[nf] = RD_B(nf, 0);
        SCHED0;
        asm volatile("s_waitcnt lgkmcnt(0)" ::: "memory");
        SCHED0;
        __builtin_amdgcn_s_setprio(1);
        #pragma unroll
        for (int mf = 0; mf < 4; mf++)
            #pragma unroll
            for (int nf = 0; nf < 4; nf++)
                acc[mf][nf] = __builtin_amdgcn_mfma_f32_16x16x32_bf16(
                    af[mf], bfr[nf], acc[mf][nf], 0, 0, 0);
        __builtin_amdgcn_s_setprio(0);
    }
#undef RD_A
#undef RD_B
#undef SCHED0

    // ---- epilogue: tanh, x-weighted, reduce over ci (m) then kk (t) ----
    // (R11-proven verbatim; wn == wt)
    const float* xn = x + (((size_t)n * CN) << 12);
    #pragma unroll
    for (int nf = 0; nf < 4; nf++) {
        int t  = T0 + wt * 64 + nf * 16 + i16;
        uint sp = ((uint)t * 58255u) >> 19;       // t/9, exact for t < 74898
        int kk = t - (int)sp * 9;
        int kh = (kk * 11) >> 5;                  // kk/3
        int kw = kk - kh * 3;
        int y  = (int)(sp >> 6) + kh - 1;
        int xw = (int)(sp & 63) + kw - 1;
        bool ok = ((unsigned)y < 64u) && ((unsigned)xw < 64u);
        int poff = (y << 6) + xw;
        float xa[4], xb[4];
        #pragma unroll
        for (int r = 0; r < 4; r++) {
            int cia = kg * 4 + r;
            xa[r] = ok ? xn[((size_t)cia << 12) + poff] : 0.f;
            xb[r] = ok ? xn[((size_t)(cia + 16) << 12) + poff] : 0.f;
        }
        float s0 = 0.f, s1 = 0.f;
        #pragma unroll
        for (int r = 0; r < 4; r++) {
            s0 = fmaf(fast_tanh(acc[0][nf][r]), xa[r], s0);
            s0 = fmaf(fast_tanh(acc[1][nf][r]), xb[r], s0);
            s1 = fmaf(fast_tanh(acc[2][nf][r]), xa[r], s1);
            s1 = fmaf(fast_tanh(acc[3][nf][r]), xb[r], s1);
        }
        s0 += __shfl_xor(s0, 16); s0 += __shfl_xor(s0, 32);
        s1 += __shfl_xor(s1, 16); s1 += __shfl_xor(s1, 32);
        if (kg == 0) {
            vred[2 * wm + 0][wt * 64 + nf * 16 + i16] = s0;
            vred[2 * wm + 1][wt * 64 + nf * 16 + i16] = s1;
        }
    }
    __syncthreads();

    if (tid < 64) {
        int g  = tid >> 4, bi = tid & 15;
        uint spA = ((uint)T0 * 58255u) >> 19;
        int sp = (int)spA + bi;
        int lo = sp * 9;     if (lo < T0) lo = T0;
        int hi = sp * 9 + 9; if (hi > T0 + 128) hi = T0 + 128;
        if (lo < hi) {
            float s = 0.f;
            for (int t = lo; t < hi; t++) s += vred[g][t - T0];
            atomicAdd(&out[(((size_t)n * CN + cg * 4 + g) << 12) + sp], s);
        }
    }
}

extern "C" void kernel_launch(void* const* d_in, const int* in_sizes, int n_in,
                              void* d_out, int out_size, void* d_ws, size_t ws_size,
                              hipStream_t stream) {
    const float* x  = (const float*)d_in[0];
    const float* w1 = (const float*)d_in[1];
    const float* w2 = (const float*)d_in[2];
    float* out = (float*)d_out;
    char* ws = (char*)d_ws;

    float*    hbuf  = (float*)ws;                       // 1 MiB
    ushort_t* Bm_bf = (ushort_t*)(ws + 1048576u);       // 8192*288*2 = 4718592 B
    ushort_t* A_bf  = (ushort_t*)(ws + 5767168u);       // 9216*288*2 = 5308416 B

    hipLaunchKernelGGL(prep_kernel, dim3(1808), dim3(256), 0, stream,
                       x, w1, w2, hbuf, A_bf, (float4*)out);
    hipLaunchKernelGGL(im2col_bf16_perm, dim3(1152), dim3(256), 0,
                       stream, hbuf, Bm_bf);
    hipLaunchKernelGGL(fused_gemm_apply, dim3(4608), dim3(256), 0, stream,
                       A_bf, Bm_bf, x, out);
}

// Round 16
// 97.350 us; speedup vs baseline: 1.2231x; 1.2231x over previous
//
#include <hip/hip_runtime.h>

typedef unsigned int uint;
typedef unsigned short ushort_t;

// Problem constants
#define CN 32          // channels
#define HW 4096        // H*W
#define KDIM 288       // C*9
#define PDIM 8192      // N*HW
#define NB 2           // batch

typedef __attribute__((ext_vector_type(8))) short bf16x8;
typedef __attribute__((ext_vector_type(4))) float f32x4;

static __device__ __forceinline__ ushort_t f2bf(float f) {
    uint u = __float_as_uint(f);
    uint r = (u + 0x7fffu + ((u >> 16) & 1u)) >> 16;
    return (ushort_t)r;
}

static __device__ __forceinline__ void gl_lds16(const void* g, void* l) {
    __builtin_amdgcn_global_load_lds(
        (const __attribute__((address_space(1))) unsigned int*)g,
        (__attribute__((address_space(3))) unsigned int*)l, 16, 0, 0);
}

static __device__ __forceinline__ float fast_tanh(float v) {
    // tanh(v) = 1 - 2*rcp(1+e^{2v}); rcp(inf)=0 -> +-1 exact; err ~1e-6
    float e = __expf(2.0f * v);
    return 1.0f - 2.0f * __builtin_amdgcn_rcpf(e + 1.0f);
}

// k-permutation within each 32-k group: 16B chunk slot s holds logical
// k = {g*32 + 4s..4s+3, g*32 + 16+4s..16+4s+3}. Lane kg's whole MFMA
// fragment (k = kg*4+j, 16+kg*4+j) is then ONE contiguous 16B LDS chunk.

// ------------- prep: conv1+relu (blocks 0..1023) | w2->bf16 perm + zero-out -
// conv1 (R16): ci split 4 ways (8 ci per thread), 1024 blocks; partials
// combined in LDS. Proven load/FMA body unchanged.
__global__ __launch_bounds__(256) void prep_kernel(
    const float* __restrict__ x, const float* __restrict__ w1,
    const float* __restrict__ w2, float* __restrict__ hout,
    ushort_t* __restrict__ A_bf, float4* __restrict__ out_zero)
{
    __shared__ float w1s[KDIM];
    __shared__ float ps[4][64][4];
    int bb = blockIdx.x;
    int tid = threadIdx.x;
    if (bb < 1024) {
        int n  = bb >> 9;
        int c  = (bb >> 4) & 31;
        int rg = bb & 15;                 // 4-row group
        for (int j = tid; j < KDIM; j += 256) w1s[j] = w1[c * KDIM + j];
        __syncthreads();

        int quarter = tid >> 6;           // ci in [quarter*8, quarter*8+8)
        int i2      = tid & 63;
        int hh      = rg * 4 + (i2 >> 4);
        int ws0     = (i2 & 15) * 4;

        float acc0 = 0.f, acc1 = 0.f, acc2 = 0.f, acc3 = 0.f;
        int ci0 = quarter * 8;
        for (int ci = ci0; ci < ci0 + 8; ci++) {
            const float* xp = x + (((size_t)(n * CN + ci)) << 12);
            #pragma unroll
            for (int kh = 0; kh < 3; kh++) {
                int y = hh + kh - 1;
                if ((unsigned)y >= 64u) continue;
                const float* row = xp + (y << 6);
                float4 v = *(const float4*)(row + ws0);
                float left  = (ws0 > 0)  ? row[ws0 - 1] : 0.f;
                float right = (ws0 < 60) ? row[ws0 + 4] : 0.f;
                float rb[6] = {left, v.x, v.y, v.z, v.w, right};
                const float* wp = &w1s[ci * 9 + kh * 3];
                #pragma unroll
                for (int kw = 0; kw < 3; kw++) {
                    float wgt = wp[kw];
                    acc0 = fmaf(wgt, rb[0 + kw], acc0);
                    acc1 = fmaf(wgt, rb[1 + kw], acc1);
                    acc2 = fmaf(wgt, rb[2 + kw], acc2);
                    acc3 = fmaf(wgt, rb[3 + kw], acc3);
                }
            }
        }
        ps[quarter][i2][0] = acc0; ps[quarter][i2][1] = acc1;
        ps[quarter][i2][2] = acc2; ps[quarter][i2][3] = acc3;
        __syncthreads();
        if (quarter == 0) {
            float4 o = make_float4(
                fmaxf(ps[0][i2][0] + ps[1][i2][0] + ps[2][i2][0] + ps[3][i2][0], 0.f),
                fmaxf(ps[0][i2][1] + ps[1][i2][1] + ps[2][i2][1] + ps[3][i2][1], 0.f),
                fmaxf(ps[0][i2][2] + ps[1][i2][2] + ps[2][i2][2] + ps[3][i2][2], 0.f),
                fmaxf(ps[0][i2][3] + ps[1][i2][3] + ps[2][i2][3] + ps[3][i2][3], 0.f));
            *(float4*)(hout + (((size_t)(n * CN + c)) << 12) + (hh << 6) + ws0) = o;
        }
    } else {
        // w2 fp32 -> bf16 k-permuted [9216][288]; also zero out (65536 float4)
        int idx = (bb - 1024) * 256 + tid;
        if (idx < 65536)
            out_zero[idx] = make_float4(0.f, 0.f, 0.f, 0.f);
        int row = idx / 36;
        int cw  = idx - row * 36;
        int g = cw >> 2, s = cw & 3;
        const float* base = w2 + (size_t)row * KDIM + g * 32;
        float4 lo = *(const float4*)(base + s * 4);
        float4 hi = *(const float4*)(base + 16 + s * 4);
        alignas(16) ushort_t o[8] = {f2bf(lo.x), f2bf(lo.y), f2bf(lo.z), f2bf(lo.w),
                                     f2bf(hi.x), f2bf(hi.y), f2bf(hi.z), f2bf(hi.w)};
        *(uint4*)(A_bf + (size_t)idx * 8) = *(const uint4*)o;
    }
}

// ------ im2col of h, P-MAJOR k-PERMUTED bf16: one 16B chunk per thread ------
__global__ __launch_bounds__(256) void im2col_bf16_perm(
    const float* __restrict__ h, ushort_t* __restrict__ Bm)
{
    int idx = blockIdx.x * 256 + threadIdx.x;   // PDIM*36 = 294912 chunks
    int p  = idx / 36;
    int cw = idx - p * 36;
    int g = cw >> 2, s = cw & 3;
    int n  = p >> 12;
    int sp = p & 4095;
    int hh = sp >> 6;
    int w  = sp & 63;
    const float* hn = h + (((size_t)n * CN) << 12);
    alignas(16) ushort_t o[8];
    #pragma unroll
    for (int j = 0; j < 8; j++) {
        int ko = (j < 4) ? (s * 4 + j) : (12 + s * 4 + j);  // 16+s*4+(j-4)
        int k  = g * 32 + ko;
        int ci = (k * 57) >> 9;            // k/9, exact for k < 4500
        int kk = k - ci * 9;
        int kh = (kk * 11) >> 5;           // kk/3
        int kw = kk - kh * 3;
        int y  = hh + kh - 1;
        int xw = w + kw - 1;
        float v = 0.f;
        if ((unsigned)y < 64u && (unsigned)xw < 64u)
            v = hn[((size_t)ci << 12) + (y << 6) + xw];
        o[j] = f2bf(v);
    }
    *(uint4*)(Bm + (size_t)idx * 8) = *(const uint4*)o;
}

// ---- fused: MFMA GEMM + tanh + apply (depth-2 prefetch, 3-buffer dbuf) -----
// (R14-proven verbatim — best measured: 76 us, 572 TF ~ the 2-phase
// structural ceiling m233; 6 schedule variants all land 76-134 us.)
__global__ __launch_bounds__(512, 4) void fused_gemm_apply(
    const ushort_t* __restrict__ A, const ushort_t* __restrict__ B,
    const float* __restrict__ x, float* __restrict__ out)
{
    __shared__ ushort_t AL[3][128 * 32];   // 3 x 8 KiB
    __shared__ ushort_t BL[3][256 * 32];   // 3 x 16 KiB
    __shared__ float vred[4][256];

    int tid = threadIdx.x;
    // bijective XCD swizzle: 2304 = 8 XCDs x 288
    int bid = blockIdx.x;
    int sb  = (bid & 7) * 288 + (bid >> 3);
    int tw  = sb % 144;
    int cg  = (sb / 144) & 7;
    int n   = sb / 1152;

    int lane = tid & 63, wv = tid >> 6;
    int wm = wv >> 2, wt = wv & 3;      // 2m x 4t wave grid
    int i16 = lane & 15, kg = lane >> 4;

    int T0 = tw * 256;
    int c8 = T0 >> 12;
    int q0 = T0 & 4095;

    // staging: per K-step, thread stages 1 A chunk + 2 B chunks (16B each)
    int cA = tid;
    int rA = cA >> 2;
    int k8A = (((cA & 3) ^ ((cA >> 3) & 3)) << 3);
    const ushort_t* srcA = A +
        (size_t)((cg * 4 + (rA >> 5)) * KDIM + (rA & 31) * 9 + c8) * KDIM + k8A;
    int cB0 = tid, cB1 = 512 + tid;
    int rB0 = cB0 >> 2, rB1 = cB1 >> 2;
    int k8B0 = (((cB0 & 3) ^ ((cB0 >> 3) & 3)) << 3);
    int k8B1 = (((cB1 & 3) ^ ((cB1 >> 3) & 3)) << 3);
    const ushort_t* srcB0 = B + (size_t)((n << 12) + q0 + rB0) * KDIM + k8B0;
    const ushort_t* srcB1 = B + (size_t)((n << 12) + q0 + rB1) * KDIM + k8B1;
    int dstA = wv * 512, dstB0 = wv * 512, dstB1 = 4096 + wv * 512;

#define STAGE(BUF, KS)                                                  \
    do { int _k0 = (KS) * 32;                                           \
        gl_lds16(srcA + _k0,  &AL[BUF][dstA]);                          \
        gl_lds16(srcB0 + _k0, &BL[BUF][dstB0]);                         \
        gl_lds16(srcB1 + _k0, &BL[BUF][dstB1]);                         \
    } while (0)

    f32x4 acc[4][4] = {};

    // prologue: tiles 0,1 in flight
    STAGE(0, 0);
    STAGE(1, 1);

    #pragma unroll
    for (int ks = 0; ks < 9; ks++) {
        int cur = ks % 3;
        if (ks < 7) {
            STAGE((ks + 2) % 3, ks + 2);
            __builtin_amdgcn_sched_barrier(0);
            asm volatile("s_waitcnt vmcnt(6)" ::: "memory");  // tile ks done
        } else if (ks == 7) {
            __builtin_amdgcn_sched_barrier(0);
            asm volatile("s_waitcnt vmcnt(3)" ::: "memory");
        } else {
            __builtin_amdgcn_sched_barrier(0);
            asm volatile("s_waitcnt vmcnt(0)" ::: "memory");
        }
        __builtin_amdgcn_sched_barrier(0);
        __builtin_amdgcn_s_barrier();       // all waves' stages visible
        __builtin_amdgcn_sched_barrier(0);

        bf16x8 af[4], bfr[4];
        #pragma unroll
        for (int mf = 0; mf < 4; mf++) {
            int row = wm * 64 + mf * 16 + i16;
            af[mf] = *(const bf16x8*)
                &AL[cur][row * 32 + ((kg ^ ((row >> 1) & 3)) << 3)];
        }
        #pragma unroll
        for (int nf = 0; nf < 4; nf++) {
            int row = wt * 64 + nf * 16 + i16;
            bfr[nf] = *(const bf16x8*)
                &BL[cur][row * 32 + ((kg ^ ((row >> 1) & 3)) << 3)];
        }
        #pragma unroll
        for (int mf = 0; mf < 4; mf++)
            #pragma unroll
            for (int nf = 0; nf < 4; nf++)
                acc[mf][nf] = __builtin_amdgcn_mfma_f32_16x16x32_bf16(
                    af[mf], bfr[nf], acc[mf][nf], 0, 0, 0);

        // reads fully retired before the WAR window opens
        __builtin_amdgcn_sched_barrier(0);
        asm volatile("s_waitcnt lgkmcnt(0)" ::: "memory");
        __builtin_amdgcn_sched_barrier(0);
        __builtin_amdgcn_s_barrier();
        __builtin_amdgcn_sched_barrier(0);
    }
#undef STAGE

    // ---- epilogue: tanh, x-weighted, reduce over ci (m) then kk (t) ----
    const float* xn = x + (((size_t)n * CN) << 12);
    #pragma unroll
    for (int nf = 0; nf < 4; nf++) {
        int t  = T0 + wt * 64 + nf * 16 + i16;
        uint sp = ((uint)t * 58255u) >> 19;       // t/9, exact for t < 74898
        int kk = t - (int)sp * 9;
        int kh = (kk * 11) >> 5;                  // kk/3
        int kw = kk - kh * 3;
        int y  = (int)(sp >> 6) + kh - 1;
        int xw = (int)(sp & 63) + kw - 1;
        bool ok = ((unsigned)y < 64u) && ((unsigned)xw < 64u);
        int poff = (y << 6) + xw;
        float xa[4], xb[4];
        #pragma unroll
        for (int r = 0; r < 4; r++) {
            int cia = kg * 4 + r;
            xa[r] = ok ? xn[((size_t)cia << 12) + poff] : 0.f;
            xb[r] = ok ? xn[((size_t)(cia + 16) << 12) + poff] : 0.f;
        }
        float s0 = 0.f, s1 = 0.f;
        #pragma unroll
        for (int r = 0; r < 4; r++) {
            s0 = fmaf(fast_tanh(acc[0][nf][r]), xa[r], s0);
            s0 = fmaf(fast_tanh(acc[1][nf][r]), xb[r], s0);
            s1 = fmaf(fast_tanh(acc[2][nf][r]), xa[r], s1);
            s1 = fmaf(fast_tanh(acc[3][nf][r]), xb[r], s1);
        }
        s0 += __shfl_xor(s0, 16); s0 += __shfl_xor(s0, 32);
        s1 += __shfl_xor(s1, 16); s1 += __shfl_xor(s1, 32);
        if (kg == 0) {
            vred[2 * wm + 0][wt * 64 + nf * 16 + i16] = s0;
            vred[2 * wm + 1][wt * 64 + nf * 16 + i16] = s1;
        }
    }
    __syncthreads();

    // ---- fold 9 t's per pixel, atomicAdd (2-way only on window boundaries) ----
    if (tid < 128) {
        int g  = tid >> 5, bi = tid & 31;
        uint spA = ((uint)T0 * 58255u) >> 19;
        int sp = (int)spA + bi;
        int lo = sp * 9;     if (lo < T0) lo = T0;
        int hi = sp * 9 + 9; if (hi > T0 + 256) hi = T0 + 256;
        if (lo < hi) {
            float s = 0.f;
            for (int t = lo; t < hi; t++) s += vred[g][t - T0];
            atomicAdd(&out[(((size_t)n * CN + cg * 4 + g) << 12) + sp], s);
        }
    }
}

extern "C" void kernel_launch(void* const* d_in, const int* in_sizes, int n_in,
                              void* d_out, int out_size, void* d_ws, size_t ws_size,
                              hipStream_t stream) {
    const float* x  = (const float*)d_in[0];
    const float* w1 = (const float*)d_in[1];
    const float* w2 = (const float*)d_in[2];
    float* out = (float*)d_out;
    char* ws = (char*)d_ws;

    float*    hbuf  = (float*)ws;                       // 1 MiB
    ushort_t* Bm_bf = (ushort_t*)(ws + 1048576u);       // 8192*288*2 = 4718592 B
    ushort_t* A_bf  = (ushort_t*)(ws + 5767168u);       // 9216*288*2 = 5308416 B

    hipLaunchKernelGGL(prep_kernel, dim3(2320), dim3(256), 0, stream,
                       x, w1, w2, hbuf, A_bf, (float4*)out);
    hipLaunchKernelGGL(im2col_bf16_perm, dim3(1152), dim3(256), 0,
                       stream, hbuf, Bm_bf);
    hipLaunchKernelGGL(fused_gemm_apply, dim3(2304), dim3(512), 0, stream,
                       A_bf, Bm_bf, x, out);
}